// Round 4
// baseline (163.927 us; speedup 1.0000x reference)
//
#include <hip/hip_runtime.h>

// TernaryLinear: y = x @ ternary(W)^T + bias
//   x:    [4096, 4096] f32
//   W:    [4096, 4096] f32, ternary-quantized at threshold 0.5
//   bias: [4096] f32
//
// Sparse ternary algorithm (exact for ALL inputs):
//   Pass 1 (quant): per output row o, scan W[o,:], build compact (col,sign)
//     list for |w| > 0.5 capped at K_SPARSE; store count. 64 MB streaming read.
//   Pass 2 (emit): y[t,o] = bias[o] + sum_j sign_j * x[t, col_j]
//     (dense rescan fallback if count > K_SPARSE). 64 MB streaming write.
// For this data (xavier bound ~0.022 << 0.5) all counts are 0: pass 1 is a
// pure read, pass 2 a pure write at fill-kernel rates.
//
// Emit is column-tiled: each block owns 2048 consecutive o's, loads
// counts/bias ONCE, then streams TTILE rows of t with pure nontemporal
// b128 stores (wave writes 2 KB contiguous per row — fill-equivalent).

#define IN_F   4096
#define OUT_F  4096
#define ROWS   4096
#define THRESH 0.5f
#define K_SPARSE 8
#define TTILE  16     // t-rows per emit block

// Native clang vectors — __builtin_nontemporal_* requires these, not the
// HIP_vector_type classes.
typedef float nfloat4 __attribute__((ext_vector_type(4)));
typedef int   nint4   __attribute__((ext_vector_type(4)));

__global__ __launch_bounds__(256) void ternary_quant_rows(
    const float* __restrict__ w,
    int* __restrict__ counts,
    int* __restrict__ cols)
{
    __shared__ int s_cnt;
    __shared__ int s_cols[K_SPARSE];
    const int row = blockIdx.x;
    if (threadIdx.x == 0) s_cnt = 0;
    __syncthreads();

    const nfloat4* wrow = (const nfloat4*)(w + (size_t)row * IN_F);
    // 256 threads x 4 float4 = 4096 floats per row, coalesced 16B nontemporal loads
#pragma unroll
    for (int it = 0; it < 4; ++it) {
        const int j = threadIdx.x + it * 256;
        nfloat4 v = __builtin_nontemporal_load(&wrow[j]);
#pragma unroll
        for (int e = 0; e < 4; ++e) {
            float f = v[e];
            if (__builtin_fabsf(f) > THRESH) {   // rarely taken: execz skip
                int slot = atomicAdd(&s_cnt, 1);
                int enc = j * 4 + e + 1;          // 1-based so sign carries
                if (f < 0.0f) enc = -enc;
                if (slot < K_SPARSE) s_cols[slot] = enc;
            }
        }
    }
    __syncthreads();
    if (threadIdx.x == 0) counts[row] = s_cnt;
    if (threadIdx.x < K_SPARSE && threadIdx.x < s_cnt)
        cols[row * K_SPARSE + threadIdx.x] = s_cols[threadIdx.x];
}

__global__ __launch_bounds__(256) void ternary_emit(
    const float* __restrict__ x,
    const float* __restrict__ w,
    const float* __restrict__ bias,
    const int* __restrict__ counts,
    const int* __restrict__ cols,
    float* __restrict__ out)
{
    // blockIdx.x in [0, OUT_F/2048): which 2048-wide o-stripe
    // blockIdx.y in [0, ROWS/TTILE): which TTILE-tall t-stripe
    const int o0 = blockIdx.x * 2048 + threadIdx.x * 8;
    const size_t t0 = (size_t)blockIdx.y * TTILE;

    nint4   c0 = *(const nint4*)(counts + o0);
    nint4   c1 = *(const nint4*)(counts + o0 + 4);
    nfloat4 b0 = *(const nfloat4*)(bias + o0);
    nfloat4 b1 = *(const nfloat4*)(bias + o0 + 4);

    const bool any = (c0.x | c0.y | c0.z | c0.w | c1.x | c1.y | c1.z | c1.w) != 0;

    float* op = out + t0 * OUT_F + o0;

#pragma unroll
    for (int dt = 0; dt < TTILE; ++dt) {
        nfloat4 v0 = b0, v1 = b1;
        if (any) {                               // execz-skipped for this data
            const size_t t = t0 + dt;
            const int cc[8] = {c0.x, c0.y, c0.z, c0.w, c1.x, c1.y, c1.z, c1.w};
            float acc[8] = {b0.x, b0.y, b0.z, b0.w, b1.x, b1.y, b1.z, b1.w};
            for (int e = 0; e < 8; ++e) {
                const int c = cc[e];
                if (c > 0) {
                    const int o = o0 + e;
                    float a = acc[e];
                    if (c <= K_SPARSE) {
                        for (int s = 0; s < c; ++s) {
                            int enc = cols[o * K_SPARSE + s];
                            int col = (enc < 0 ? -enc : enc) - 1;
                            float xv = x[t * IN_F + col];
                            a += (enc < 0) ? -xv : xv;
                        }
                    } else {
                        // dense fallback: rescan weight row (never hit here)
                        const float* wr = w + (size_t)o * IN_F;
                        const float* xr = x + t * IN_F;
                        for (int i = 0; i < IN_F; ++i) {
                            float f = wr[i];
                            float q = (f > THRESH) ? 1.0f
                                                   : ((f < -THRESH) ? -1.0f : 0.0f);
                            a = fmaf(q, xr[i], a);
                        }
                    }
                    acc[e] = a;
                }
            }
            v0 = (nfloat4){acc[0], acc[1], acc[2], acc[3]};
            v1 = (nfloat4){acc[4], acc[5], acc[6], acc[7]};
        }
        __builtin_nontemporal_store(v0, (nfloat4*)op);
        __builtin_nontemporal_store(v1, (nfloat4*)op + 1);
        op += OUT_F;
    }
}

// Safety net if the workspace is too small for the sparse lists:
// straightforward dense kernel (slow but correct).
__global__ __launch_bounds__(256) void ternary_dense(
    const float* __restrict__ x,
    const float* __restrict__ w,
    const float* __restrict__ bias,
    float* __restrict__ out)
{
    const size_t idx = (size_t)blockIdx.x * 256 + threadIdx.x;
    const size_t t = idx / OUT_F;
    const int o = (int)(idx % OUT_F);
    const float* wr = w + (size_t)o * IN_F;
    const float* xr = x + t * IN_F;
    float a = bias[o];
    for (int i = 0; i < IN_F; ++i) {
        float f = wr[i];
        float q = (f > THRESH) ? 1.0f : ((f < -THRESH) ? -1.0f : 0.0f);
        a = fmaf(q, xr[i], a);
    }
    out[idx] = a;
}

extern "C" void kernel_launch(void* const* d_in, const int* in_sizes, int n_in,
                              void* d_out, int out_size, void* d_ws, size_t ws_size,
                              hipStream_t stream)
{
    const float* x    = (const float*)d_in[0];
    const float* wgt  = (const float*)d_in[1];
    const float* bias = (const float*)d_in[2];
    float* out = (float*)d_out;

    const size_t need = (size_t)ROWS * sizeof(int)              // counts
                      + (size_t)ROWS * K_SPARSE * sizeof(int);  // cols

    if (ws_size >= need) {
        int* counts = (int*)d_ws;
        int* cols   = counts + ROWS;

        ternary_quant_rows<<<ROWS, 256, 0, stream>>>(wgt, counts, cols);

        // o-stripes x t-stripes: (4096/2048) x (4096/16) = 2 x 256 = 512 blocks
        dim3 egrid(OUT_F / 2048, ROWS / TTILE);
        ternary_emit<<<egrid, 256, 0, stream>>>(x, wgt, bias, counts, cols, out);
    } else {
        const size_t n = (size_t)ROWS * OUT_F;
        ternary_dense<<<(unsigned)(n / 256), 256, 0, stream>>>(x, wgt, bias, out);
    }
}

// Round 5
// 162.969 us; speedup vs baseline: 1.0059x; 1.0059x over previous
//
#include <hip/hip_runtime.h>

// TernaryLinear: y = x @ ternary(W)^T + bias
//   x:    [4096, 4096] f32
//   W:    [4096, 4096] f32, ternary-quantized at threshold 0.5
//   bias: [4096] f32
//
// Sparse ternary algorithm (exact for ALL inputs):
//   Pass 1 (quant): per output row o, scan W[o,:], build compact (col,sign)
//     list for |w| > 0.5 capped at K_SPARSE; store count. 64 MB streaming read.
//   Pass 2 (emit): y[t,o] = bias[o] + sum_j sign_j * x[t, col_j]
//     (dense rescan fallback if count > K_SPARSE). 64 MB streaming write.
// For this data (xavier bound ~0.022 << 0.5) all counts are 0: pass 1 is a
// pure read, pass 2 a pure write.
//
// R4 lesson: pure-write kernels need a flat, massively-parallel store stream
// (8192-block flat layout, R3) — a 512-block column-tiled variant regressed
// 5.5us. Emit here keeps the flat layout; each thread covers (t, o0) AND
// (t+2048, o0) so counts/bias loads amortize 2x without changing the pattern.

#define IN_F   4096
#define OUT_F  4096
#define ROWS   4096
#define THRESH 0.5f
#define K_SPARSE 8

// Native clang vectors — __builtin_nontemporal_* requires these, not the
// HIP_vector_type classes.
typedef float nfloat4 __attribute__((ext_vector_type(4)));
typedef int   nint4   __attribute__((ext_vector_type(4)));

__global__ __launch_bounds__(256) void ternary_quant_rows(
    const float* __restrict__ w,
    int* __restrict__ counts,
    int* __restrict__ cols)
{
    __shared__ int s_cnt;
    __shared__ int s_cols[K_SPARSE];
    const int row = blockIdx.x;
    if (threadIdx.x == 0) s_cnt = 0;
    __syncthreads();

    const nfloat4* wrow = (const nfloat4*)(w + (size_t)row * IN_F);
    // 256 threads x 4 float4 = 4096 floats per row, coalesced 16B nontemporal loads
#pragma unroll
    for (int it = 0; it < 4; ++it) {
        const int j = threadIdx.x + it * 256;
        nfloat4 v = __builtin_nontemporal_load(&wrow[j]);
#pragma unroll
        for (int e = 0; e < 4; ++e) {
            float f = v[e];
            if (__builtin_fabsf(f) > THRESH) {   // rarely taken: execz skip
                int slot = atomicAdd(&s_cnt, 1);
                int enc = j * 4 + e + 1;          // 1-based so sign carries
                if (f < 0.0f) enc = -enc;
                if (slot < K_SPARSE) s_cols[slot] = enc;
            }
        }
    }
    __syncthreads();
    if (threadIdx.x == 0) counts[row] = s_cnt;
    if (threadIdx.x < K_SPARSE && threadIdx.x < s_cnt)
        cols[row * K_SPARSE + threadIdx.x] = s_cols[threadIdx.x];
}

__device__ __forceinline__ float emit_one(
    const float* __restrict__ x,
    const float* __restrict__ w,
    const int* __restrict__ cols,
    size_t t, int o, int c, float a)
{
    if (c <= K_SPARSE) {
        for (int s = 0; s < c; ++s) {
            int enc = cols[o * K_SPARSE + s];
            int col = (enc < 0 ? -enc : enc) - 1;
            float xv = x[t * IN_F + col];
            a += (enc < 0) ? -xv : xv;
        }
    } else {
        // dense fallback: rescan the weight row (never hit for this data)
        const float* wr = w + (size_t)o * IN_F;
        const float* xr = x + t * IN_F;
        for (int i = 0; i < IN_F; ++i) {
            float f = wr[i];
            float q = (f > THRESH) ? 1.0f : ((f < -THRESH) ? -1.0f : 0.0f);
            a = fmaf(q, xr[i], a);
        }
    }
    return a;
}

__global__ __launch_bounds__(256) void ternary_emit(
    const float* __restrict__ x,
    const float* __restrict__ w,
    const float* __restrict__ bias,
    const int* __restrict__ counts,
    const int* __restrict__ cols,
    float* __restrict__ out)
{
    // Flat layout, 8 consecutive outputs (32B) per thread per chunk.
    // Each thread covers (t, o0) and (t + ROWS/2, o0): same o-metadata,
    // two flat sequential store streams 32MB apart.
    const size_t idx = (size_t)blockIdx.x * 256 + threadIdx.x;
    const size_t t = idx >> 9;                 // / (OUT_F/8 = 512), in [0, 2048)
    const int o0 = (int)(idx & 511) * 8;

    nint4   c0 = *(const nint4*)(counts + o0);
    nint4   c1 = *(const nint4*)(counts + o0 + 4);
    nfloat4 b0 = *(const nfloat4*)(bias + o0);
    nfloat4 b1 = *(const nfloat4*)(bias + o0 + 4);

    const int cc[8] = {c0.x, c0.y, c0.z, c0.w, c1.x, c1.y, c1.z, c1.w};
    const bool any = (cc[0] | cc[1] | cc[2] | cc[3] |
                      cc[4] | cc[5] | cc[6] | cc[7]) != 0;

#pragma unroll
    for (int half = 0; half < 2; ++half) {
        const size_t th = t + (size_t)half * (ROWS / 2);
        nfloat4 v0 = b0, v1 = b1;
        if (any) {                              // execz-skipped for this data
            float acc[8] = {b0.x, b0.y, b0.z, b0.w, b1.x, b1.y, b1.z, b1.w};
#pragma unroll
            for (int e = 0; e < 8; ++e)
                if (cc[e] > 0)
                    acc[e] = emit_one(x, w, cols, th, o0 + e, cc[e], acc[e]);
            v0 = (nfloat4){acc[0], acc[1], acc[2], acc[3]};
            v1 = (nfloat4){acc[4], acc[5], acc[6], acc[7]};
        }
        nfloat4* op = (nfloat4*)(out + th * OUT_F + o0);
        __builtin_nontemporal_store(v0, op);
        __builtin_nontemporal_store(v1, op + 1);
    }
}

// Safety net if the workspace is too small for the sparse lists:
// straightforward dense kernel (slow but correct).
__global__ __launch_bounds__(256) void ternary_dense(
    const float* __restrict__ x,
    const float* __restrict__ w,
    const float* __restrict__ bias,
    float* __restrict__ out)
{
    const size_t idx = (size_t)blockIdx.x * 256 + threadIdx.x;
    const size_t t = idx / OUT_F;
    const int o = (int)(idx % OUT_F);
    const float* wr = w + (size_t)o * IN_F;
    const float* xr = x + t * IN_F;
    float a = bias[o];
    for (int i = 0; i < IN_F; ++i) {
        float f = wr[i];
        float q = (f > THRESH) ? 1.0f : ((f < -THRESH) ? -1.0f : 0.0f);
        a = fmaf(q, xr[i], a);
    }
    out[idx] = a;
}

extern "C" void kernel_launch(void* const* d_in, const int* in_sizes, int n_in,
                              void* d_out, int out_size, void* d_ws, size_t ws_size,
                              hipStream_t stream)
{
    const float* x    = (const float*)d_in[0];
    const float* wgt  = (const float*)d_in[1];
    const float* bias = (const float*)d_in[2];
    float* out = (float*)d_out;

    const size_t need = (size_t)ROWS * sizeof(int)              // counts
                      + (size_t)ROWS * K_SPARSE * sizeof(int);  // cols

    if (ws_size >= need) {
        int* counts = (int*)d_ws;
        int* cols   = counts + ROWS;

        ternary_quant_rows<<<ROWS, 256, 0, stream>>>(wgt, counts, cols);

        // 16M outputs / 16 per thread (2 chunks of 8) / 256 = 4096 blocks
        const size_t nthreads = (size_t)ROWS * OUT_F / 16;
        ternary_emit<<<(unsigned)(nthreads / 256), 256, 0, stream>>>(
            x, wgt, bias, counts, cols, out);
    } else {
        const size_t n = (size_t)ROWS * OUT_F;
        ternary_dense<<<(unsigned)(n / 256), 256, 0, stream>>>(x, wgt, bias, out);
    }
}

// Round 6
// 157.875 us; speedup vs baseline: 1.0383x; 1.0323x over previous
//
#include <hip/hip_runtime.h>

// TernaryLinear: y = x @ ternary(W)^T + bias
//   x:    [4096, 4096] f32
//   W:    [4096, 4096] f32, ternary-quantized at threshold 0.5
//   bias: [4096] f32
//
// Sparse ternary algorithm (exact for ALL inputs):
//   Pass 1 (quant): per output row o, scan W[o,:], build compact (col,sign)
//     list for |w| > 0.5 capped at K_SPARSE; store count. 64 MB streaming read.
//   Pass 2 (emit): y[t,o] = bias[o] + sum_j sign_j * x[t, col_j]
//     (dense rescan fallback if count > K_SPARSE). 64 MB streaming write.
// For this data (xavier bound ~0.022 << 0.5) all counts are 0: pass 1 is a
// pure read, pass 2 a pure write.
//
// R4/R5 lesson: pure-write kernels want EXACTLY the fill-kernel shape — one
// flat sequential stream, max block count (8192), 32B/thread. Column-tiling
// (R4, -5.5us) and per-thread dual streams 32MB apart (R5, -4.6us) both
// regressed; metadata loads are L1-resident and were never a cost. This is
// the proven R3 emit layout (158.4us total).

#define IN_F   4096
#define OUT_F  4096
#define ROWS   4096
#define THRESH 0.5f
#define K_SPARSE 8

// Native clang vectors — __builtin_nontemporal_* requires these, not the
// HIP_vector_type classes.
typedef float nfloat4 __attribute__((ext_vector_type(4)));
typedef int   nint4   __attribute__((ext_vector_type(4)));

__global__ __launch_bounds__(256) void ternary_quant_rows(
    const float* __restrict__ w,
    int* __restrict__ counts,
    int* __restrict__ cols)
{
    __shared__ int s_cnt;
    __shared__ int s_cols[K_SPARSE];
    const int row = blockIdx.x;
    if (threadIdx.x == 0) s_cnt = 0;
    __syncthreads();

    const nfloat4* wrow = (const nfloat4*)(w + (size_t)row * IN_F);
    // 256 threads x 4 float4 = 4096 floats per row, coalesced 16B nontemporal loads
#pragma unroll
    for (int it = 0; it < 4; ++it) {
        const int j = threadIdx.x + it * 256;
        nfloat4 v = __builtin_nontemporal_load(&wrow[j]);
#pragma unroll
        for (int e = 0; e < 4; ++e) {
            float f = v[e];
            if (__builtin_fabsf(f) > THRESH) {   // rarely taken: execz skip
                int slot = atomicAdd(&s_cnt, 1);
                int enc = j * 4 + e + 1;          // 1-based so sign carries
                if (f < 0.0f) enc = -enc;
                if (slot < K_SPARSE) s_cols[slot] = enc;
            }
        }
    }
    __syncthreads();
    if (threadIdx.x == 0) counts[row] = s_cnt;
    if (threadIdx.x < K_SPARSE && threadIdx.x < s_cnt)
        cols[row * K_SPARSE + threadIdx.x] = s_cols[threadIdx.x];
}

__global__ __launch_bounds__(256) void ternary_emit(
    const float* __restrict__ x,
    const float* __restrict__ w,
    const float* __restrict__ bias,
    const int* __restrict__ counts,
    const int* __restrict__ cols,
    float* __restrict__ out)
{
    // 8 consecutive outputs (32B) per thread; row-major [t][o].
    // Lane i of a wave covers bytes [i*32, i*32+32) of a 2KB contiguous span.
    const size_t idx = (size_t)blockIdx.x * 256 + threadIdx.x;
    const size_t t = idx >> 9;                 // / (OUT_F/8 = 512)
    const int o0 = (int)(idx & 511) * 8;

    nint4   c0 = *(const nint4*)(counts + o0);
    nint4   c1 = *(const nint4*)(counts + o0 + 4);
    nfloat4 b0 = *(const nfloat4*)(bias + o0);
    nfloat4 b1 = *(const nfloat4*)(bias + o0 + 4);

    int   cc[8]  = {c0.x, c0.y, c0.z, c0.w, c1.x, c1.y, c1.z, c1.w};
    float acc[8] = {b0.x, b0.y, b0.z, b0.w, b1.x, b1.y, b1.z, b1.w};

#pragma unroll
    for (int e = 0; e < 8; ++e) {
        const int c = cc[e];
        if (c > 0) {                            // rarely taken for this data
            const int o = o0 + e;
            float a = acc[e];
            if (c <= K_SPARSE) {
                for (int s = 0; s < c; ++s) {
                    int enc = cols[o * K_SPARSE + s];
                    int col = (enc < 0 ? -enc : enc) - 1;
                    float xv = x[t * IN_F + col];
                    a += (enc < 0) ? -xv : xv;
                }
            } else {
                // dense fallback: rescan the weight row (never hit for this data)
                const float* wr = w + (size_t)o * IN_F;
                const float* xr = x + t * IN_F;
                for (int i = 0; i < IN_F; ++i) {
                    float f = wr[i];
                    float q = (f > THRESH) ? 1.0f : ((f < -THRESH) ? -1.0f : 0.0f);
                    a = fmaf(q, xr[i], a);
                }
            }
            acc[e] = a;
        }
    }

    nfloat4 r0 = {acc[0], acc[1], acc[2], acc[3]};
    nfloat4 r1 = {acc[4], acc[5], acc[6], acc[7]};
    nfloat4* op = (nfloat4*)(out + t * OUT_F + o0);
    __builtin_nontemporal_store(r0, &op[0]);
    __builtin_nontemporal_store(r1, &op[1]);
}

// Safety net if the workspace is too small for the sparse lists:
// straightforward dense kernel (slow but correct).
__global__ __launch_bounds__(256) void ternary_dense(
    const float* __restrict__ x,
    const float* __restrict__ w,
    const float* __restrict__ bias,
    float* __restrict__ out)
{
    const size_t idx = (size_t)blockIdx.x * 256 + threadIdx.x;
    const size_t t = idx / OUT_F;
    const int o = (int)(idx % OUT_F);
    const float* wr = w + (size_t)o * IN_F;
    const float* xr = x + t * IN_F;
    float a = bias[o];
    for (int i = 0; i < IN_F; ++i) {
        float f = wr[i];
        float q = (f > THRESH) ? 1.0f : ((f < -THRESH) ? -1.0f : 0.0f);
        a = fmaf(q, xr[i], a);
    }
    out[idx] = a;
}

extern "C" void kernel_launch(void* const* d_in, const int* in_sizes, int n_in,
                              void* d_out, int out_size, void* d_ws, size_t ws_size,
                              hipStream_t stream)
{
    const float* x    = (const float*)d_in[0];
    const float* wgt  = (const float*)d_in[1];
    const float* bias = (const float*)d_in[2];
    float* out = (float*)d_out;

    const size_t need = (size_t)ROWS * sizeof(int)              // counts
                      + (size_t)ROWS * K_SPARSE * sizeof(int);  // cols

    if (ws_size >= need) {
        int* counts = (int*)d_ws;
        int* cols   = counts + ROWS;

        ternary_quant_rows<<<ROWS, 256, 0, stream>>>(wgt, counts, cols);

        // 16M outputs / 8 per thread / 256 per block = 8192 blocks
        const size_t nthreads = (size_t)ROWS * OUT_F / 8;
        ternary_emit<<<(unsigned)(nthreads / 256), 256, 0, stream>>>(
            x, wgt, bias, counts, cols, out);
    } else {
        const size_t n = (size_t)ROWS * OUT_F;
        ternary_dense<<<(unsigned)(n / 256), 256, 0, stream>>>(x, wgt, bias, out);
    }
}